// Round 5
// baseline (282.003 us; speedup 1.0000x reference)
//
#include <hip/hip_runtime.h>
#include <math.h>

#define E 288
#define NSEQ 2048
#define BATCH 4
#define NH 8
#define HD 36
#define BH (BATCH * NH)      // 32
#define ROWS (BATCH * NSEQ)  // 8192

typedef _Float16 half8_t __attribute__((ext_vector_type(8)));
typedef _Float16 half4_t __attribute__((ext_vector_type(4)));
typedef float f32x4 __attribute__((ext_vector_type(4)));
typedef int i32x4 __attribute__((ext_vector_type(4)));

// ===========================================================================
// split_w: W (fp32, [k][n]) -> transposed fp16 hi: whalf[m][n*E + k]
// ===========================================================================
__global__ __launch_bounds__(256) void split_w_kernel(
    const float* __restrict__ Wq, const float* __restrict__ Wk,
    const float* __restrict__ Wv, const float* __restrict__ Wo,
    _Float16* __restrict__ whalf) {
  const int idx = blockIdx.x * 256 + threadIdx.x;  // 0 .. 4*E*E-1
  const int m = idx / (E * E);
  const int rem = idx - m * (E * E);
  const int k = rem / E, n = rem - k * E;
  const float* W = (m == 0) ? Wq : (m == 1) ? Wk : (m == 2) ? Wv : Wo;
  whalf[(size_t)m * (E * E) + n * E + k] = (_Float16)W[rem];
}

// ===========================================================================
// QKV projection, single-term fp16 MFMA (outputs are fp16 anyway).
// Tile 128 rows x 96 cols; K chunks of 32; register prefetch across barriers.
// Outputs: mode 0/1 -> q16/k16 [bh][n][64] (cols 36..63 pre-zeroed by memset)
//          mode 2   -> v16 [bh][n][48] (pad cols garbage, contained later)
// ===========================================================================
#define PM 128
#define PN 96
#define LDA 40  // LDS row stride in halfs

struct QKVArgs {
  const float* x[3];
  const _Float16* w[3];
  const float* bias[3];
  _Float16* out[3];
};

__global__ __launch_bounds__(256, 4) void proj_qkv_kernel(QKVArgs A) {
  __shared__ __align__(16) _Float16 a_h[PM * LDA];
  __shared__ __align__(16) _Float16 w_h[PN * LDA];

  const int tid = threadIdx.x;
  const int lane = tid & 63, wv = tid >> 6;
  const int quad = lane >> 4, l15 = lane & 15;
  const int mode = blockIdx.z;
  const float* __restrict__ x = A.x[mode];
  const _Float16* __restrict__ wh = A.w[mode];
  const int row0 = blockIdx.x * PM, col0 = blockIdx.y * PN;

  f32x4 acc[2][6];
#pragma unroll
  for (int t = 0; t < 2; ++t)
#pragma unroll
    for (int nt = 0; nt < 6; ++nt) acc[t][nt] = (f32x4){0.f, 0.f, 0.f, 0.f};

  // prefetch chunk 0
  float4 apre[4];
  i32x4 wpre[2];
#pragma unroll
  for (int iu = 0; iu < 4; ++iu) {
    const int i = tid + 256 * iu, r = i >> 3, c4 = i & 7;
    apre[iu] = *(const float4*)&x[(size_t)(row0 + r) * E + c4 * 4];
  }
  {
    const int n = tid >> 2, qd = tid & 3;
    wpre[0] = *(const i32x4*)&wh[(size_t)(col0 + n) * E + qd * 8];
    if (tid < 128) {
      const int i = tid + 256, n2 = i >> 2, q2 = i & 3;
      wpre[1] = *(const i32x4*)&wh[(size_t)(col0 + n2) * E + q2 * 8];
    }
  }

  for (int kk = 0; kk < E; kk += 32) {
    __syncthreads();
    // write prefetched regs to LDS (A converted to fp16)
#pragma unroll
    for (int iu = 0; iu < 4; ++iu) {
      const int i = tid + 256 * iu, r = i >> 3, c4 = i & 7;
      half4_t hv = {(_Float16)apre[iu].x, (_Float16)apre[iu].y,
                    (_Float16)apre[iu].z, (_Float16)apre[iu].w};
      *(half4_t*)&a_h[r * LDA + c4 * 4] = hv;
    }
    {
      const int n = tid >> 2, qd = tid & 3;
      *(i32x4*)&w_h[n * LDA + qd * 8] = wpre[0];
      if (tid < 128) {
        const int i = tid + 256, n2 = i >> 2, q2 = i & 3;
        *(i32x4*)&w_h[n2 * LDA + q2 * 8] = wpre[1];
      }
    }
    // prefetch next chunk
    if (kk + 32 < E) {
#pragma unroll
      for (int iu = 0; iu < 4; ++iu) {
        const int i = tid + 256 * iu, r = i >> 3, c4 = i & 7;
        apre[iu] = *(const float4*)&x[(size_t)(row0 + r) * E + kk + 32 + c4 * 4];
      }
      const int n = tid >> 2, qd = tid & 3;
      wpre[0] = *(const i32x4*)&wh[(size_t)(col0 + n) * E + kk + 32 + qd * 8];
      if (tid < 128) {
        const int i = tid + 256, n2 = i >> 2, q2 = i & 3;
        wpre[1] = *(const i32x4*)&wh[(size_t)(col0 + n2) * E + kk + 32 + q2 * 8];
      }
    }
    __syncthreads();
    // compute
    half8_t ah[2];
#pragma unroll
    for (int t = 0; t < 2; ++t)
      ah[t] = *(const half8_t*)&a_h[(wv * 32 + t * 16 + l15) * LDA + quad * 8];
#pragma unroll
    for (int nt = 0; nt < 6; ++nt) {
      const half8_t bh = *(const half8_t*)&w_h[(nt * 16 + l15) * LDA + quad * 8];
#pragma unroll
      for (int t = 0; t < 2; ++t)
        acc[t][nt] = __builtin_amdgcn_mfma_f32_16x16x32_f16(ah[t], bh, acc[t][nt], 0, 0, 0);
    }
  }

  // epilogue: fp16 stores to head-major layouts
  const float* __restrict__ bias = A.bias[mode];
  _Float16* __restrict__ outp = A.out[mode];
  const float scale = (mode == 0) ? (1.0f / 6.0f) : 1.0f;
  const int ostride = (mode == 2) ? 48 : 64;
#pragma unroll
  for (int nt = 0; nt < 6; ++nt) {
    const int col = col0 + nt * 16 + l15;
    const int h = col / 36, d = col - h * 36;
    const float bc = bias[col];
#pragma unroll
    for (int t = 0; t < 2; ++t) {
#pragma unroll
      for (int r = 0; r < 4; ++r) {
        const int row = row0 + wv * 32 + t * 16 + quad * 4 + r;
        const int b = row >> 11, n = row & (NSEQ - 1);
        outp[((size_t)(b * NH + h) * NSEQ + n) * ostride + d] =
            (_Float16)((acc[t][nt][r] + bc) * scale);
      }
    }
  }
}

// ===========================================================================
// fp16 MFMA flash attention. QB=256 (4 waves x 64 rows), KT=64, SPLIT=4.
// Q fragments direct from global (q16 zero-padded). K via register prefetch
// + swizzled LDS. V transposed in LDS from fp16 rows. No-max softmax =>
// linear (acc,sum) partials. pi(c)=(c&15)*4+(c>>4) key interleave for P/V.
// ===========================================================================
#define QB 256
#define KT 64
#define SPLIT 4
#define LDK 64

__device__ __forceinline__ int sw(int row, int col) {
  return row * LDK + ((((col >> 3) ^ row) & 7) << 3) + (col & 7);
}

__global__ __launch_bounds__(256, 3) void attn_mfma_kernel(
    const _Float16* __restrict__ q16, const _Float16* __restrict__ k16,
    const _Float16* __restrict__ v16, float* __restrict__ pacc,
    float* __restrict__ psum) {
  __shared__ __align__(16) _Float16 khalf[KT * LDK];    // [key][d]
  __shared__ __align__(16) _Float16 vthalf[48 * LDK];   // [vdim][pikey]
  __shared__ __align__(16) _Float16 pbuf[QB * LDK];     // [row][pikey]

  const int tid = threadIdx.x;
  const int lane = tid & 63;
  const int w = tid >> 6;
  const int quad = lane >> 4;
  const int l15 = lane & 15;

  const int bh = blockIdx.y;
  const int q0 = blockIdx.x * QB;
  const int chunk = blockIdx.z;

  // Q A-fragments direct from global: [stripe t][kchunk]
  half8_t qf[4][2];
#pragma unroll
  for (int t = 0; t < 4; ++t)
#pragma unroll
    for (int kc = 0; kc < 2; ++kc)
      qf[t][kc] = *(const half8_t*)&q16[((size_t)bh * NSEQ + q0 + w * 64 + t * 16 + l15) * 64 +
                                        kc * 32 + quad * 8];

  f32x4 oacc[4][3];
#pragma unroll
  for (int t = 0; t < 4; ++t)
#pragma unroll
    for (int nt = 0; nt < 3; ++nt) oacc[t][nt] = (f32x4){0.f, 0.f, 0.f, 0.f};
  float ssum[4][4];
#pragma unroll
  for (int t = 0; t < 4; ++t)
#pragma unroll
    for (int r = 0; r < 4; ++r) ssum[t][r] = 0.f;

  const int kt0 = chunk * (NSEQ / (SPLIT * KT));
  const int kt1 = kt0 + NSEQ / (SPLIT * KT);

  // prefetch K tile kt0 into regs (2 b128 per thread)
  i32x4 kpre[2];
#pragma unroll
  for (int iu = 0; iu < 2; ++iu) {
    const int u = tid + 256 * iu, c = u >> 3, ch = u & 7;
    kpre[iu] = *(const i32x4*)&k16[((size_t)bh * NSEQ + kt0 * KT + c) * 64 + ch * 8];
  }

  for (int kt = kt0; kt < kt1; ++kt) {
    const int kbase = kt * KT;
    __syncthreads();  // previous tile fully consumed
    // K regs -> LDS (swizzled)
#pragma unroll
    for (int iu = 0; iu < 2; ++iu) {
      const int u = tid + 256 * iu, c = u >> 3, ch = u & 7;
      *(i32x4*)&khalf[sw(c, ch * 8)] = kpre[iu];
    }
    // V: global fp16 rows -> LDS transposed + pi-interleaved
    for (int u = tid; u < KT * 6; u += 256) {
      const int c = u / 6, ch = u - c * 6;
      const half8_t vv =
          *(const half8_t*)&v16[((size_t)bh * NSEQ + kbase + c) * 48 + ch * 8];
      const int pc = ((c & 15) << 2) | (c >> 4);
#pragma unroll
      for (int j = 0; j < 8; ++j) vthalf[sw(ch * 8 + j, pc)] = vv[j];
    }
    // prefetch next K tile
    if (kt + 1 < kt1) {
#pragma unroll
      for (int iu = 0; iu < 2; ++iu) {
        const int u = tid + 256 * iu, c = u >> 3, ch = u & 7;
        kpre[iu] = *(const i32x4*)&k16[((size_t)bh * NSEQ + (kt + 1) * KT + c) * 64 + ch * 8];
      }
    }
    __syncthreads();

    // ---- QK^T + exp + P-write, in two t-halves (VGPR control)
#pragma unroll
    for (int th = 0; th < 2; ++th) {
      f32x4 sc[2][4];
#pragma unroll
      for (int s = 0; s < 4; ++s) {
        const half8_t kf0 = *(const half8_t*)&khalf[sw(s * 16 + l15, quad * 8)];
        const half8_t kf1 = *(const half8_t*)&khalf[sw(s * 16 + l15, 32 + quad * 8)];
#pragma unroll
        for (int tt = 0; tt < 2; ++tt) {
          const int t = th * 2 + tt;
          f32x4 c0 = __builtin_amdgcn_mfma_f32_16x16x32_f16(
              qf[t][0], kf0, (f32x4){0.f, 0.f, 0.f, 0.f}, 0, 0, 0);
          sc[tt][s] = __builtin_amdgcn_mfma_f32_16x16x32_f16(qf[t][1], kf1, c0, 0, 0, 0);
        }
      }
#pragma unroll
      for (int tt = 0; tt < 2; ++tt) {
        const int t = th * 2 + tt;
#pragma unroll
        for (int r = 0; r < 4; ++r) {
          const float p0 = __expf(sc[tt][0][r]);
          const float p1 = __expf(sc[tt][1][r]);
          const float p2 = __expf(sc[tt][2][r]);
          const float p3 = __expf(sc[tt][3][r]);
          ssum[t][r] += (p0 + p1) + (p2 + p3);
          half4_t ph = {(_Float16)p0, (_Float16)p1, (_Float16)p2, (_Float16)p3};
          *(half4_t*)&pbuf[sw(w * 64 + t * 16 + quad * 4 + r, l15 * 4)] = ph;
        }
      }
    }
    // no barrier: pbuf rows [64w,64w+64) are wave-private; DS in-order per wave

    // ---- P @ V
#pragma unroll
    for (int kc = 0; kc < 2; ++kc) {
      half8_t vf[3];
#pragma unroll
      for (int nt = 0; nt < 3; ++nt)
        vf[nt] = *(const half8_t*)&vthalf[sw(nt * 16 + l15, kc * 32 + quad * 8)];
#pragma unroll
      for (int t = 0; t < 4; ++t) {
        const half8_t af = *(const half8_t*)&pbuf[sw(w * 64 + t * 16 + l15, kc * 32 + quad * 8)];
#pragma unroll
        for (int nt = 0; nt < 3; ++nt)
          oacc[t][nt] = __builtin_amdgcn_mfma_f32_16x16x32_f16(af, vf[nt], oacc[t][nt], 0, 0, 0);
      }
    }
  }

  // ---- write raw partials
#pragma unroll
  for (int t = 0; t < 4; ++t) {
#pragma unroll
    for (int r = 0; r < 4; ++r) {
      float s = ssum[t][r];
      s += __shfl_xor(s, 1);
      s += __shfl_xor(s, 2);
      s += __shfl_xor(s, 4);
      s += __shfl_xor(s, 8);
      const int row = q0 + w * 64 + t * 16 + quad * 4 + r;
      const size_t gr = (size_t)chunk * (BH * NSEQ) + (size_t)bh * NSEQ + row;
      if (l15 == 0) psum[gr] = s;
#pragma unroll
      for (int nt = 0; nt < 3; ++nt) {
        const int col = nt * 16 + l15;
        if (col < HD) pacc[gr * HD + col] = oacc[t][nt][r];
      }
    }
  }
}

// ===========================================================================
// Combine split-K partials -> pre-split (hi,lo) fp16 input for the O proj
// ===========================================================================
__global__ __launch_bounds__(256) void combine_kernel(
    const float* __restrict__ pacc, const float* __restrict__ psum,
    _Float16* __restrict__ ab_hi, _Float16* __restrict__ ab_lo) {
  const int idx = blockIdx.x * 256 + threadIdx.x;
  if (idx >= BH * NSEQ * HD) return;
  const int gr = idx / HD;
  const int d = idx - gr * HD;

  float a = 0.f, s = 0.f;
#pragma unroll
  for (int c = 0; c < SPLIT; ++c) {
    a += pacc[((size_t)c * (BH * NSEQ) + gr) * HD + d];
    s += psum[(size_t)c * (BH * NSEQ) + gr];
  }
  const float val = a / s;
  const int bh = gr >> 11;
  const int n = gr & (NSEQ - 1);
  const int b = bh >> 3, h = bh & 7;
  const size_t o = ((size_t)(b * NSEQ + n)) * E + h * HD + d;
  const _Float16 hi = (_Float16)val;
  ab_hi[o] = hi;
  ab_lo[o] = (_Float16)(val - (float)hi);
}

// ===========================================================================
// O projection: 2-term (x_hi + x_lo) @ W_hi, fp32 out, tile 128x96, prefetch
// ===========================================================================
__global__ __launch_bounds__(256, 4) void proj_o_kernel(
    const _Float16* __restrict__ xh, const _Float16* __restrict__ xl,
    const _Float16* __restrict__ wh, const float* __restrict__ bias,
    float* __restrict__ out) {
  __shared__ __align__(16) _Float16 a_h[PM * LDA];
  __shared__ __align__(16) _Float16 a_l[PM * LDA];
  __shared__ __align__(16) _Float16 w_h[PN * LDA];

  const int tid = threadIdx.x;
  const int lane = tid & 63, wv = tid >> 6;
  const int quad = lane >> 4, l15 = lane & 15;
  const int row0 = blockIdx.x * PM, col0 = blockIdx.y * PN;

  f32x4 acc[2][6];
#pragma unroll
  for (int t = 0; t < 2; ++t)
#pragma unroll
    for (int nt = 0; nt < 6; ++nt) acc[t][nt] = (f32x4){0.f, 0.f, 0.f, 0.f};

  i32x4 hpre[2], lpre[2], wpre[2];
#pragma unroll
  for (int iu = 0; iu < 2; ++iu) {
    const int i = tid + 256 * iu, r = i >> 2, qd = i & 3;
    hpre[iu] = *(const i32x4*)&xh[(size_t)(row0 + r) * E + qd * 8];
    lpre[iu] = *(const i32x4*)&xl[(size_t)(row0 + r) * E + qd * 8];
  }
  {
    const int n = tid >> 2, qd = tid & 3;
    wpre[0] = *(const i32x4*)&wh[(size_t)(col0 + n) * E + qd * 8];
    if (tid < 128) {
      const int i = tid + 256, n2 = i >> 2, q2 = i & 3;
      wpre[1] = *(const i32x4*)&wh[(size_t)(col0 + n2) * E + q2 * 8];
    }
  }

  for (int kk = 0; kk < E; kk += 32) {
    __syncthreads();
#pragma unroll
    for (int iu = 0; iu < 2; ++iu) {
      const int i = tid + 256 * iu, r = i >> 2, qd = i & 3;
      *(i32x4*)&a_h[r * LDA + qd * 8] = hpre[iu];
      *(i32x4*)&a_l[r * LDA + qd * 8] = lpre[iu];
    }
    {
      const int n = tid >> 2, qd = tid & 3;
      *(i32x4*)&w_h[n * LDA + qd * 8] = wpre[0];
      if (tid < 128) {
        const int i = tid + 256, n2 = i >> 2, q2 = i & 3;
        *(i32x4*)&w_h[n2 * LDA + q2 * 8] = wpre[1];
      }
    }
    if (kk + 32 < E) {
#pragma unroll
      for (int iu = 0; iu < 2; ++iu) {
        const int i = tid + 256 * iu, r = i >> 2, qd = i & 3;
        hpre[iu] = *(const i32x4*)&xh[(size_t)(row0 + r) * E + kk + 32 + qd * 8];
        lpre[iu] = *(const i32x4*)&xl[(size_t)(row0 + r) * E + kk + 32 + qd * 8];
      }
      const int n = tid >> 2, qd = tid & 3;
      wpre[0] = *(const i32x4*)&wh[(size_t)(col0 + n) * E + kk + 32 + qd * 8];
      if (tid < 128) {
        const int i = tid + 256, n2 = i >> 2, q2 = i & 3;
        wpre[1] = *(const i32x4*)&wh[(size_t)(col0 + n2) * E + kk + 32 + q2 * 8];
      }
    }
    __syncthreads();

    half8_t ah[2], al[2];
#pragma unroll
    for (int t = 0; t < 2; ++t) {
      ah[t] = *(const half8_t*)&a_h[(wv * 32 + t * 16 + l15) * LDA + quad * 8];
      al[t] = *(const half8_t*)&a_l[(wv * 32 + t * 16 + l15) * LDA + quad * 8];
    }
#pragma unroll
    for (int nt = 0; nt < 6; ++nt) {
      const half8_t bh = *(const half8_t*)&w_h[(nt * 16 + l15) * LDA + quad * 8];
#pragma unroll
      for (int t = 0; t < 2; ++t) {
        acc[t][nt] = __builtin_amdgcn_mfma_f32_16x16x32_f16(ah[t], bh, acc[t][nt], 0, 0, 0);
        acc[t][nt] = __builtin_amdgcn_mfma_f32_16x16x32_f16(al[t], bh, acc[t][nt], 0, 0, 0);
      }
    }
  }

#pragma unroll
  for (int nt = 0; nt < 6; ++nt) {
    const int col = col0 + nt * 16 + l15;
    const float bc = bias[col];
#pragma unroll
    for (int t = 0; t < 2; ++t) {
#pragma unroll
      for (int r = 0; r < 4; ++r) {
        const int row = row0 + wv * 32 + t * 16 + quad * 4 + r;
        out[(size_t)row * E + col] = acc[t][nt][r] + bc;
      }
    }
  }
}

// ===========================================================================
extern "C" void kernel_launch(void* const* d_in, const int* in_sizes, int n_in,
                              void* d_out, int out_size, void* d_ws,
                              size_t ws_size, hipStream_t stream) {
  const float* query = (const float*)d_in[0];
  const float* key_ = (const float*)d_in[1];
  const float* value = (const float*)d_in[2];
  const float* Wq = (const float*)d_in[3];
  const float* bq = (const float*)d_in[4];
  const float* Wk = (const float*)d_in[5];
  const float* bk = (const float*)d_in[6];
  const float* Wv = (const float*)d_in[7];
  const float* bv = (const float*)d_in[8];
  const float* Wo = (const float*)d_in[9];
  const float* bo = (const float*)d_in[10];
  float* out = (float*)d_out;

  // workspace layout
  _Float16* q16 = (_Float16*)d_ws;                       // 32*2048*64
  _Float16* k16 = q16 + (size_t)BH * NSEQ * 64;          // 32*2048*64
  _Float16* v16 = k16 + (size_t)BH * NSEQ * 64;          // 32*2048*48
  float* pacc = (float*)(v16 + (size_t)BH * NSEQ * 48);  // SPLIT*BH*NSEQ*HD
  float* psum = pacc + (size_t)SPLIT * BH * NSEQ * HD;   // SPLIT*BH*NSEQ
  _Float16* whalf = (_Float16*)(psum + (size_t)SPLIT * BH * NSEQ);  // 4*E*E
  _Float16* ab_hi = whalf + (size_t)4 * E * E;           // ROWS*E
  _Float16* ab_lo = ab_hi + (size_t)ROWS * E;            // ROWS*E

  // zero the d-padding of q16/k16 (cols 36..63 must be 0 for the QK MFMA)
  hipMemsetAsync(q16, 0, (size_t)2 * BH * NSEQ * 64 * sizeof(_Float16), stream);

  split_w_kernel<<<(4 * E * E) / 256, 256, 0, stream>>>(Wq, Wk, Wv, Wo, whalf);

  QKVArgs qa;
  qa.x[0] = query; qa.x[1] = key_; qa.x[2] = value;
  qa.w[0] = whalf + 0 * (size_t)(E * E);
  qa.w[1] = whalf + 1 * (size_t)(E * E);
  qa.w[2] = whalf + 2 * (size_t)(E * E);
  qa.bias[0] = bq; qa.bias[1] = bk; qa.bias[2] = bv;
  qa.out[0] = q16; qa.out[1] = k16; qa.out[2] = v16;
  proj_qkv_kernel<<<dim3(ROWS / PM, E / PN, 3), 256, 0, stream>>>(qa);

  attn_mfma_kernel<<<dim3(NSEQ / QB, BH, SPLIT), 256, 0, stream>>>(
      q16, k16, v16, pacc, psum);

  combine_kernel<<<(BH * NSEQ * HD + 255) / 256, 256, 0, stream>>>(pacc, psum,
                                                                   ab_hi, ab_lo);

  proj_o_kernel<<<dim3(ROWS / PM, E / PN), 256, 0, stream>>>(
      ab_hi, ab_lo, whalf + 3 * (size_t)(E * E), bo, out);
}